// Round 9
// baseline (195.723 us; speedup 1.0000x reference)
//
#include <hip/hip_runtime.h>
#include <hip/hip_bf16.h>
#include <math.h>

typedef __bf16 v8bf __attribute__((ext_vector_type(8)));
typedef __bf16 v4bf __attribute__((ext_vector_type(4)));
typedef short  v4s  __attribute__((ext_vector_type(4)));
typedef float  v4f  __attribute__((ext_vector_type(4)));
typedef unsigned short u16;

static_assert(sizeof(v8bf) == 16, "v8bf must be 16B");

// ---------- helpers ----------
__device__ __forceinline__ u16 f2bf(float f) {
  __hip_bfloat16 h = __float2bfloat16(f);
  return *reinterpret_cast<u16*>(&h);
}
__device__ __forceinline__ v4f mfma16(v8bf a, v8bf b, v4f c) {
  return __builtin_amdgcn_mfma_f32_16x16x32_bf16(a, b, c, 0, 0, 0);
}
// K=16 shape for PV: A = P (in-register from S^T C/D), B = V from LDS b64.
__device__ __forceinline__ v4f mfma16k16(v4bf a, v4bf b, v4f c) {
#if __has_builtin(__builtin_amdgcn_mfma_f32_16x16x16_bf16)
  return __builtin_amdgcn_mfma_f32_16x16x16_bf16(a, b, c, 0, 0, 0);
#else
  union { v4bf f; v4s s; } ua, ub;
  ua.f = a; ub.f = b;
  return __builtin_amdgcn_mfma_f32_16x16x16bf16_1k(ua.s, ub.s, c, 0, 0, 0);
#endif
}
// async global->LDS, 16B per lane; lptr must be wave-uniform base (HW adds lane*16)
__device__ __forceinline__ void async16(const u16* g, u16* l) {
  __builtin_amdgcn_global_load_lds(
      (__attribute__((address_space(1))) void*)(void*)g,
      (__attribute__((address_space(3))) void*)l, 16, 0, 0);
}

// ---------- prep: z<4 -> weight transpose+convert; z==4 -> x f32->bf16 ----------
__global__ void prep(const float* __restrict__ x, const float* __restrict__ Wq,
                     const float* __restrict__ Wk, const float* __restrict__ Wv,
                     const float* __restrict__ Wo, u16* __restrict__ Wt,
                     u16* __restrict__ xb) {
  int tx = threadIdx.x, ty = threadIdx.y;
  if (blockIdx.z == 4) {  // convert x: 1024 threads x 4 f32 per block
    int bid = blockIdx.y * 32 + blockIdx.x;
    int i = (bid * 1024 + ty * 32 + tx) * 4;
    float4 v = *(const float4*)(x + i);
    ushort4 o;
    o.x = f2bf(v.x); o.y = f2bf(v.y); o.z = f2bf(v.z); o.w = f2bf(v.w);
    *(ushort4*)(xb + i) = o;
    return;
  }
  __shared__ float tile[32][33];
  const float* src = (blockIdx.z == 0) ? Wq : (blockIdx.z == 1) ? Wk : (blockIdx.z == 2) ? Wv : Wo;
  int k0 = blockIdx.x * 32, n0 = blockIdx.y * 32;
  tile[ty][tx] = src[(size_t)(k0 + ty) * 1024 + n0 + tx];
  __syncthreads();
  Wt[(size_t)(blockIdx.z * 1024 + n0 + ty) * 1024 + k0 + tx] = f2bf(tile[tx][ty]);
}

// ---------- GEMM1 v5 (r8-proven): 256x256 tile, 8 waves, BK=64, 2-dbuf 128KB ----------
__global__ __launch_bounds__(512) void gemm_qkv(const u16* __restrict__ xb,
                                                const u16* __restrict__ Wt,
                                                u16* __restrict__ Qb,
                                                u16* __restrict__ Kb,
                                                u16* __restrict__ Vt) {
  extern __shared__ __align__(16) u16 lds[];   // 131072 B
  u16* sA = lds;           // [2][256*64]
  u16* sB = lds + 32768;   // [2][256*64]

  const int t = threadIdx.x;
  const int w = t >> 6, l = t & 63;
  const int quad = l >> 4, low = l & 15;
  const int wm = (w & 1) * 128, wn = (w >> 1) * 64;
  const int bm = blockIdx.x, bn = blockIdx.y;

  const int srow = l >> 3;
  const int cg = (l & 7) ^ srow;

  auto SA_ = [&](int R0, int kb, u16* dst) {
    async16(xb + (size_t)(bm * 256 + R0 + w * 8 + srow) * 1024 + kb + cg * 8,
            dst + (R0 + w * 8) * 64);
  };
  auto SB_ = [&](int R0, int kb, u16* dst) {
    async16(Wt + (size_t)(bn * 256 + R0 + w * 8 + srow) * 1024 + kb + cg * 8,
            dst + (R0 + w * 8) * 64);
  };

  v4f acc[8][4] = {};

  SB_(0, 0, sB); SB_(64, 0, sB); SB_(128, 0, sB); SB_(192, 0, sB);
  SA_(0, 0, sA); SA_(128, 0, sA); SA_(64, 0, sA); SA_(192, 0, sA);

#pragma unroll 2
  for (int kt = 0; kt < 16; ++kt) {
    const int p = kt & 1;
    const u16* pa = sA + p * 16384;
    const u16* pb = sB + p * 16384;
    u16* nA = sA + (p ^ 1) * 16384;
    u16* nB = sB + (p ^ 1) * 16384;
    const int nkb = (kt + 1) * 64;
    const bool more = (kt < 15);

    asm volatile("s_waitcnt lgkmcnt(0)" ::: "memory");
    asm volatile("s_waitcnt vmcnt(2)" ::: "memory");
    __builtin_amdgcn_s_barrier();

    v8bf bf[2][4];
#pragma unroll
    for (int j = 0; j < 4; j++) {
      const int rb = wn + j * 16 + low, sw = rb & 7;
      bf[0][j] = *(const v8bf*)(pb + rb * 64 + ((quad ^ sw) * 8));
      bf[1][j] = *(const v8bf*)(pb + rb * 64 + (((4 + quad) ^ sw) * 8));
    }
#pragma unroll
    for (int ph = 0; ph < 4; ++ph) {
      if (ph == 2) {
        if (more) asm volatile("s_waitcnt vmcnt(4)" ::: "memory");
        else      asm volatile("s_waitcnt vmcnt(0)" ::: "memory");
        __builtin_amdgcn_s_barrier();
      }
      v8bf a0k0, a0k1, a1k0, a1k1;
      {
        const int ra = wm + (2 * ph) * 16 + low, sw = ra & 7;
        a0k0 = *(const v8bf*)(pa + ra * 64 + ((quad ^ sw) * 8));
        a0k1 = *(const v8bf*)(pa + ra * 64 + (((4 + quad) ^ sw) * 8));
      }
      {
        const int ra = wm + (2 * ph + 1) * 16 + low, sw = ra & 7;
        a1k0 = *(const v8bf*)(pa + ra * 64 + ((quad ^ sw) * 8));
        a1k1 = *(const v8bf*)(pa + ra * 64 + (((4 + quad) ^ sw) * 8));
      }
      if (more) {
        if (ph == 0)      { SB_(0, nkb, nB);   SB_(64, nkb, nB); }
        else if (ph == 1) { SB_(128, nkb, nB); SB_(192, nkb, nB); }
        else if (ph == 2) { SA_(0, nkb, nA);   SA_(128, nkb, nA); }
        else              { SA_(64, nkb, nA);  SA_(192, nkb, nA); }
      }
      __builtin_amdgcn_s_setprio(1);
#pragma unroll
      for (int j = 0; j < 4; j++) {
        acc[2 * ph][j]     = mfma16(a0k0, bf[0][j], acc[2 * ph][j]);
        acc[2 * ph][j]     = mfma16(a0k1, bf[1][j], acc[2 * ph][j]);
        acc[2 * ph + 1][j] = mfma16(a1k0, bf[0][j], acc[2 * ph + 1][j]);
        acc[2 * ph + 1][j] = mfma16(a1k1, bf[1][j], acc[2 * ph + 1][j]);
      }
      __builtin_amdgcn_s_setprio(0);
    }
  }

  const int zone = bn >> 2;   // 0=Q 1=K 2=V (256 | 1024, uniform per block)
  const float qsc = (zone == 0) ? 0.18033688011112042f : 1.0f;
#pragma unroll
  for (int i = 0; i < 8; i++) {
    int m0 = bm * 256 + wm + i * 16 + quad * 4;
#pragma unroll
    for (int j = 0; j < 4; j++) {
      int nn = (bn * 256 + wn + j * 16 + low) & 1023;
      if (zone == 0) {
#pragma unroll
        for (int r = 0; r < 4; r++)
          Qb[(size_t)(m0 + r) * 1024 + nn] = f2bf(acc[i][j][r] * qsc);
      } else if (zone == 1) {
#pragma unroll
        for (int r = 0; r < 4; r++)
          Kb[(size_t)(m0 + r) * 1024 + nn] = f2bf(acc[i][j][r]);
      } else {
        int bb = m0 >> 11, s = m0 & 2047;  // m0..m0+3 stay within one batch
#pragma unroll
        for (int r = 0; r < 4; r++)
          Vt[(size_t)(bb * 1024 + nn) * 2048 + s + r] = f2bf(acc[i][j][r]);
      }
    }
  }
}

// ---------- GEMM2: out[4096][1024] = ctx @ Wo + bo, f32 out (r0 structure) ----------
__global__ __launch_bounds__(256) void gemm_out(const u16* __restrict__ ctx,
                                                const u16* __restrict__ Wt,
                                                const float* __restrict__ bo,
                                                float* __restrict__ out) {
  __shared__ __align__(16) u16 sA[128 * 32];
  __shared__ __align__(16) u16 sB[64 * 32];
  const u16* Bt = Wt + (size_t)3072 * 1024;
  v4f acc[4][2] = {};
  const int bm = blockIdx.x, bn = blockIdx.y;
  const int t = threadIdx.x, w = t >> 6, l = t & 63, quad = l >> 4, low = l & 15;
  const int wm = (w & 1) * 64, wn = (w >> 1) * 32;
  const int rowA = bm * 128 + w * 32 + (l >> 2);
  const int rowB = bn * 64 + w * 16 + (l >> 2);
  const int col8 = (l & 3) * 8;
  u16* la = sA + w * 1024;
  u16* lb = sB + w * 512;

  for (int kb = 0; kb < 1024; kb += 32) {
    async16(ctx + (size_t)rowA * 1024 + kb + col8, la);
    async16(ctx + (size_t)(rowA + 16) * 1024 + kb + col8, la + 512);
    async16(Bt + (size_t)rowB * 1024 + kb + col8, lb);
    __syncthreads();
    v8bf af[4], bfr[2];
#pragma unroll
    for (int i = 0; i < 4; i++)
      af[i] = *(const v8bf*)(sA + (wm + i * 16 + low) * 32 + quad * 8);
#pragma unroll
    for (int j = 0; j < 2; j++)
      bfr[j] = *(const v8bf*)(sB + (wn + j * 16 + low) * 32 + quad * 8);
#pragma unroll
    for (int i = 0; i < 4; i++)
#pragma unroll
      for (int j = 0; j < 2; j++)
        acc[i][j] = mfma16(af[i], bfr[j], acc[i][j]);
    __syncthreads();
  }
#pragma unroll
  for (int i = 0; i < 4; i++) {
    int m0 = bm * 128 + wm + i * 16 + quad * 4;
#pragma unroll
    for (int j = 0; j < 2; j++) {
      int n = bn * 64 + wn + j * 16 + low;
      float bias = bo[n];
#pragma unroll
      for (int r = 0; r < 4; r++)
        out[(size_t)(m0 + r) * 1024 + n] = acc[i][j][r] + bias;
    }
  }
}

// ---------- flash attention v9: 2 Q-frags per wave (32 q-rows), v6 skeleton ----------
// r8 analysis: v6/v7's LDS traffic is 96KB/iter/block (32KB staged + 64KB read)
// because all 4 waves read the FULL K and V tiles; ~half of attn's 44 us is
// LDS bandwidth. v9 doubles arithmetic intensity per LDS byte: each wave owns
// TWO 16-row Q fragments (rows qw0=tile*128+w*16 and qw1=qw0+64); K/V frags
// are read ONCE and feed both fragments' MFMAs. Block q-tile = 128 rows ->
// half the blocks re-stream K/V (total staging bytes halve too).
// Skeleton = v6 exact (best measured): 2-buf 32KB LDS, __syncthreads pipeline,
// proven swizzles, descending tiles (LPT), grid 512 = 2 blocks/CU.
// Causal mask: dm = (it >= nkt-2), per-frag test key > qr_f. At it==nkt-1
// frag0's test is all-true automatically (keys >= qw0+64 > all frag0 rows),
// so one rule covers the whole 128x128 diagonal block.
__global__ __launch_bounds__(256) void attn(const u16* __restrict__ Qb,
                                            const u16* __restrict__ Kb,
                                            const u16* __restrict__ Vt,
                                            u16* __restrict__ ctx) {
  __shared__ __align__(16) u16 sK[2][4096];   // [key][64 d] swizzled, 8KB per buf
  __shared__ __align__(16) u16 sV[2][4096];   // [d][64 keys] swizzled
  const int t = threadIdx.x, w = t >> 6, l = t & 63, quad = l >> 4, low = l & 15;
  const int h = blockIdx.x, tile = 15 - blockIdx.y, b = blockIdx.z;
  const int qw0 = tile * 128 + w * 16, qw1 = qw0 + 64;
  const int nkt = 2 * (tile + 1);

  const u16* kbase = Kb + (size_t)(b * 2048) * 1024 + h * 64;   // + key*1024
  const u16* vbase = Vt + (size_t)(b * 1024 + h * 64) * 2048;   // + d*2048 + s

  // staging lane constants: row = w*8 + srow (+32), swizzled chunk cg
  const int srow = l >> 3;
  const int cg = (l & 7) ^ srow;

  // Q fragments for both 16-row halves (B-operand for S^T; pre-scaled in gemm_qkv)
  const u16* qp0 = Qb + (size_t)(b * 2048 + qw0 + low) * 1024 + h * 64;
  v8bf qa00 = *(const v8bf*)(qp0 + quad * 8);
  v8bf qa01 = *(const v8bf*)(qp0 + 32 + quad * 8);
  const u16* qp1 = Qb + (size_t)(b * 2048 + qw1 + low) * 1024 + h * 64;
  v8bf qa10 = *(const v8bf*)(qp1 + quad * 8);
  v8bf qa11 = *(const v8bf*)(qp1 + 32 + quad * 8);

  float li0 = 0.f, li1 = 0.f;
  v4f o0[4] = {}, o1[4] = {};

  {  // stage tile 0 into buf 0 (v6 verbatim)
    const u16* kg = kbase + (size_t)(w * 8 + srow) * 1024 + cg * 8;
    async16(kg, &sK[0][w * 512]);
    async16(kg + (size_t)32 * 1024, &sK[0][2048 + w * 512]);
    const u16* vg = vbase + (size_t)(w * 8 + srow) * 2048 + cg * 8;
    async16(vg, &sV[0][w * 512]);
    async16(vg + (size_t)32 * 2048, &sV[0][2048 + w * 512]);
  }

  for (int it = 0; it < nkt; it++) {
    __syncthreads();  // staging of buf[it&1] complete; buf[(it+1)&1] free
    const int kb = it * 64;
    const int cur = it & 1;
    if (it + 1 < nkt) {  // prefetch next tile (flies during compute)
      const int nb = (it + 1) & 1;
      const u16* kg = kbase + (size_t)(kb + 64 + w * 8 + srow) * 1024 + cg * 8;
      async16(kg, &sK[nb][w * 512]);
      async16(kg + (size_t)32 * 1024, &sK[nb][2048 + w * 512]);
      const u16* vg = vbase + (size_t)(w * 8 + srow) * 2048 + kb + 64 + cg * 8;
      async16(vg, &sV[nb][w * 512]);
      async16(vg + (size_t)32 * 2048, &sV[nb][2048 + w * 512]);
    }

    // S^T = K Q^T : K-frags read ONCE, feed both Q fragments
    v4f s0[4] = {}, s1[4] = {};
#pragma unroll
    for (int cf = 0; cf < 4; cf++) {
      const int key = cf * 16 + low;
      v8bf kf0 = *(const v8bf*)(&sK[cur][key * 64 + ((quad ^ (key & 7)) * 8)]);
      v8bf kf1 = *(const v8bf*)(&sK[cur][key * 64 + (((4 + quad) ^ (key & 7)) * 8)]);
      s0[cf] = mfma16(kf0, qa00, s0[cf]);
      s0[cf] = mfma16(kf1, qa01, s0[cf]);
      s1[cf] = mfma16(kf0, qa10, s1[cf]);
      s1[cf] = mfma16(kf1, qa11, s1[cf]);
    }

    // exp + lane-local denominators; P packed in-register as PV A-frags
    const bool dm = (it >= nkt - 2);
    const int qr0 = qw0 + low, qr1 = qw1 + low;
    v4bf pf0[4], pf1[4];
#pragma unroll
    for (int cf = 0; cf < 4; cf++)
#pragma unroll
      for (int r = 0; r < 4; r++) {
        float e0 = __builtin_amdgcn_exp2f(s0[cf][r]);
        float e1 = __builtin_amdgcn_exp2f(s1[cf][r]);
        if (dm) {
          const int key = kb + cf * 16 + quad * 4 + r;
          if (key > qr0) e0 = 0.f;
          if (key > qr1) e1 = 0.f;
        }
        li0 += e0; li1 += e1;
        pf0[cf][r] = (__bf16)e0;
        pf1[cf][r] = (__bf16)e1;
      }

    // PV: V-frags read ONCE, feed both output fragments
#pragma unroll
    for (int df = 0; df < 4; df++) {
      const int d = df * 16 + low;
#pragma unroll
      for (int cf = 0; cf < 4; cf++) {
        const int c2 = cf * 2 + (quad >> 1);
        const v4bf vf = *(const v4bf*)(&sV[cur][d * 64 + ((c2 ^ (d & 7)) * 8) + (quad & 1) * 4]);
        o0[df] = mfma16k16(pf0[cf], vf, o0[df]);
        o1[df] = mfma16k16(pf1[cf], vf, o1[df]);
      }
    }
  }

  // denominators: li_f(lane) covers qrow qwf+low after reducing across quads
  li0 += __shfl_xor(li0, 16);
  li0 += __shfl_xor(li0, 32);
  li1 += __shfl_xor(li1, 16);
  li1 += __shfl_xor(li1, 32);

  // epilogue: o C/D rows = qwf+quad*4+r, cols = df*16+low
#pragma unroll
  for (int r = 0; r < 4; r++) {
    float l0 = __shfl(li0, quad * 4 + r);
    float l1 = __shfl(li1, quad * 4 + r);
    float inv0 = 1.f / l0, inv1 = 1.f / l1;
    int row0 = b * 2048 + qw0 + quad * 4 + r;
    int row1 = b * 2048 + qw1 + quad * 4 + r;
#pragma unroll
    for (int df = 0; df < 4; df++) {
      ctx[(size_t)row0 * 1024 + h * 64 + df * 16 + low] = f2bf(o0[df][r] * inv0);
      ctx[(size_t)row1 * 1024 + h * 64 + df * 16 + low] = f2bf(o1[df][r] * inv1);
    }
  }
}

// ---------- launch ----------
extern "C" void kernel_launch(void* const* d_in, const int* in_sizes, int n_in,
                              void* d_out, int out_size, void* d_ws, size_t ws_size,
                              hipStream_t stream) {
  const float* x  = (const float*)d_in[0];
  const float* Wq = (const float*)d_in[1];
  const float* Wk = (const float*)d_in[2];
  const float* Wv = (const float*)d_in[3];
  const float* Wo = (const float*)d_in[4];
  const float* bo = (const float*)d_in[5];
  float* out = (float*)d_out;

  char* ws = (char*)d_ws;
  u16* xb  = (u16*)(ws);                          // [4096][1024] bf16 = 8 MB
  u16* Wt  = (u16*)(ws + 8ull * 1024 * 1024);     // [4096][1024] bf16 = 8 MB
  u16* Qb  = (u16*)(ws + 16ull * 1024 * 1024);    // [4096][1024] bf16 = 8 MB (pre-scaled)
  u16* Kb  = (u16*)(ws + 24ull * 1024 * 1024);    // [4096][1024] bf16 = 8 MB
  u16* Vt  = (u16*)(ws + 32ull * 1024 * 1024);    // [2*1024][2048] bf16 = 8 MB
  u16* ctx = (u16*)(ws + 40ull * 1024 * 1024);    // [4096][1024] bf16 = 8 MB

  static bool cfg = false;
  if (!cfg) {
    hipFuncSetAttribute((const void*)gemm_qkv,
                        hipFuncAttributeMaxDynamicSharedMemorySize, 131072);
    cfg = true;
  }

  prep<<<dim3(32, 32, 5), dim3(32, 32, 1), 0, stream>>>(x, Wq, Wk, Wv, Wo, Wt, xb);
  gemm_qkv<<<dim3(16, 12, 1), dim3(512, 1, 1), 131072, stream>>>(xb, Wt, Qb, Kb, Vt);
  attn<<<dim3(16, 16, 2), dim3(256, 1, 1), 0, stream>>>(Qb, Kb, Vt, ctx);
  gemm_out<<<dim3(32, 16, 1), dim3(256, 1, 1), 0, stream>>>(ctx, Wt, bo, out);
}